// Round 1
// baseline (1155.039 us; speedup 1.0000x reference)
//
#include <hip/hip_runtime.h>
#include <cfloat>

// Problem dims (fixed): z_e [32,64,64,64] NCHW fp32, embedding [1024,64] fp32
// Flat rows n = b*4096 + h*64 + w  (N = 131072, D = 64, K = 1024)
// Out layout (concat, fp32): [0]=vq_loss, [1..8388608]=z_q NCHW,
//                            [8388609]=perplexity, [8388610..]=encodings [N,1024]
// ws layout: ws[0]=loss accum (float), ws[1..1024]=counts (int), ws[1025..2048]=e2 (float)

__global__ __launch_bounds__(256) void vq_prep(const float* __restrict__ emb,
                                               float* __restrict__ ws) {
  #pragma clang fp contract(off)
  int gid = blockIdx.x * 256 + threadIdx.x;   // 0..1023
  if (gid == 0) ws[0] = 0.0f;
  ((int*)ws)[1 + gid] = 0;
  // e2[k] = numpy-pairwise sum of squares over 64 elems:
  // r[j] = sum_{i = j, j+8, ..} fl(e_i^2), then ((r0+r1)+(r2+r3))+((r4+r5)+(r6+r7))
  const float* e = emb + (gid << 6);
  float r[8];
  #pragma unroll
  for (int j = 0; j < 8; ++j) r[j] = e[j] * e[j];
  #pragma unroll
  for (int i = 8; i < 64; i += 8) {
    #pragma unroll
    for (int j = 0; j < 8; ++j) { float s = e[i + j] * e[i + j]; r[j] = r[j] + s; }
  }
  ws[1025 + gid] = ((r[0] + r[1]) + (r[2] + r[3])) + ((r[4] + r[5]) + (r[6] + r[7]));
}

__global__ __launch_bounds__(256) void vq_main(const float* __restrict__ ze,
                                               const float* __restrict__ emb,
                                               float* __restrict__ ws,
                                               float* __restrict__ out) {
  int wave = (blockIdx.x << 2) + (threadIdx.x >> 6);  // 0..2047
  int lane = threadIdx.x & 63;                        // = w
  int b = wave >> 6;
  int h = wave & 63;

  // ---- load x[64]: z_e[b, d, h, w], coalesced along w per d ----
  const float* xin = ze + (b << 18) + (h << 6) + lane;
  float x[64];
  #pragma unroll
  for (int d = 0; d < 64; ++d) x[d] = xin[d << 12];

  // ---- x2: replicate numpy pairwise-sum order exactly (no fma contraction) ----
  float x2;
  {
    #pragma clang fp contract(off)
    float r[8];
    #pragma unroll
    for (int j = 0; j < 8; ++j) r[j] = x[j] * x[j];
    #pragma unroll
    for (int i = 8; i < 64; i += 8) {
      #pragma unroll
      for (int j = 0; j < 8; ++j) { float s = x[i + j] * x[i + j]; r[j] = r[j] + s; }
    }
    x2 = ((r[0] + r[1]) + (r[2] + r[3])) + ((r[4] + r[5]) + (r[6] + r[7]));
  }

  const float* e2w = ws + 1025;
  float* lossp = ws;
  int* counts = (int*)ws + 1;
  float* zq  = out + 1;
  float* enc = out + 8388610;

  int n0 = wave << 6;  // first row of this wave's 64 rows
  // zero-stream this wave's own encodings region (64 rows * 1024 f32 = 32768 float2)
  // enc byte offset 8388610*4 ≡ 8 (mod 16) -> float2 (8B) stores are aligned
  float2* encz = (float2*)enc + ((size_t)n0 << 9) + lane;
  const float2 z2 = make_float2(0.0f, 0.0f);

  float best = FLT_MAX;
  int bidx = 0;
  const float4* E4 = (const float4*)emb;

  for (int k2 = 0; k2 < 512; ++k2) {
    #pragma unroll
    for (int u = 0; u < 2; ++u) {
      int k = (k2 << 1) + u;
      const float4* ek = E4 + (k << 4);  // wave-uniform address -> s_load
      float a0 = 0.0f, a1 = 0.0f, a2 = 0.0f, a3 = 0.0f;
      #pragma unroll
      for (int j = 0; j < 16; ++j) {
        float4 ev = ek[j];
        a0 = fmaf(x[(j << 2) + 0], ev.x, a0);
        a1 = fmaf(x[(j << 2) + 1], ev.y, a1);
        a2 = fmaf(x[(j << 2) + 2], ev.z, a2);
        a3 = fmaf(x[(j << 2) + 3], ev.w, a3);
      }
      float acc  = (a0 + a1) + (a2 + a3);
      float t    = x2 + e2w[k];          // fl(x2 + e2) like numpy broadcast temp
      float dist = fmaf(-2.0f, acc, t);  // == fl(t - fl(2*acc)) since 2*acc exact
      if (dist < best) { best = dist; bidx = k; }  // strict < = first-index argmin
    }
    encz[(size_t)k2 << 6] = z2;  // interleaved one-hot zero streaming
  }

  // ---- epilogue: z_q write (NCHW), loss partial, histogram, one-hot 1.0 ----
  const float* esel = emb + (bidx << 6);
  float* zqp = zq + (b << 18) + (h << 6) + lane;
  float lsum = 0.0f;
  #pragma unroll
  for (int d = 0; d < 64; ++d) {
    float v = esel[d];           // per-lane gather (L1/L2 resident, 256KB table)
    float df = v - x[d];
    lsum = fmaf(df, df, lsum);
    zqp[d << 12] = v;            // coalesced along w
  }
  #pragma unroll
  for (int off = 32; off > 0; off >>= 1) lsum += __shfl_down(lsum, off, 64);
  if (lane == 0) atomicAdd(lossp, lsum);
  atomicAdd(&counts[bidx], 1);

  // drain the zero stores before overwriting with 1.0 (same-wave region)
  asm volatile("s_waitcnt vmcnt(0)" ::: "memory");
  enc[((n0 + lane) << 10) + bidx] = 1.0f;
}

__global__ __launch_bounds__(1024) void vq_fin(const float* __restrict__ ws,
                                               float* __restrict__ out) {
  __shared__ float sm[16];
  int t = threadIdx.x;  // 0..1023 = k
  const int* counts = (const int*)ws + 1;
  float c = (float)counts[t];
  float p = c * (1.0f / 131072.0f);        // exact: sum of 0/1 exact, /2^17 exact
  float s = p * logf(p + 1e-10f);
  #pragma unroll
  for (int off = 32; off > 0; off >>= 1) s += __shfl_down(s, off, 64);
  if ((t & 63) == 0) sm[t >> 6] = s;
  __syncthreads();
  if (t == 0) {
    float v = 0.0f;
    #pragma unroll
    for (int i = 0; i < 16; ++i) v += sm[i];
    out[8388609] = expf(-v);               // perplexity
    float m = ws[0] / 8388608.0f;          // mean (z_q - z)^2
    out[0] = 0.25f * m + m;                // commitment + e2z
  }
}

extern "C" void kernel_launch(void* const* d_in, const int* in_sizes, int n_in,
                              void* d_out, int out_size, void* d_ws, size_t ws_size,
                              hipStream_t stream) {
  const float* ze  = (const float*)d_in[0];
  const float* emb = (const float*)d_in[1];
  float* out = (float*)d_out;
  float* ws  = (float*)d_ws;   // needs 2049 * 4B ≈ 8.2 KB
  vq_prep<<<4, 256, 0, stream>>>(emb, ws);
  vq_main<<<512, 256, 0, stream>>>(ze, emb, ws, out);
  vq_fin<<<1, 1024, 0, stream>>>(ws, out);
}